// Round 10
// baseline (54.173 us; speedup 1.0000x reference)
//
#include <hip/hip_runtime.h>
#include <math.h>

#define B_ 8
#define T_ 2048
#define C_ 1024
#define H_ 64

typedef __attribute__((ext_vector_type(8))) short bf16x8;
typedef __attribute__((ext_vector_type(4))) float f32x4;
typedef __attribute__((ext_vector_type(16))) float f32x16;
typedef __attribute__((ext_vector_type(4))) unsigned u32x4;
typedef __attribute__((ext_vector_type(2))) unsigned u32x2;

static __device__ __forceinline__ short f2bf(float f) {
    unsigned u = __float_as_uint(f);
    unsigned r = (u + 0x7FFFu + ((u >> 16) & 1u)) >> 16;   // RNE
    return (short)r;
}

// hardware packed f32->bf16 (RNE)
static __device__ __forceinline__ unsigned cvt_pk_bf16(float lo, float hi) {
    unsigned r;
    asm("v_cvt_pk_bf16_f32 %0, %1, %2" : "=v"(r) : "v"(lo), "v"(hi));
    return r;
}

// permlane swaps via builtins (return both results; alias-safe)
static __device__ __forceinline__ u32x2 p32(unsigned a, unsigned b) {
    return __builtin_amdgcn_permlane32_swap(a, b, false, false);
}
static __device__ __forceinline__ float xmax32(float x) {
    u32x2 r = p32(__float_as_uint(x), __float_as_uint(x));
    return fmaxf(__uint_as_float(r[0]), __uint_as_float(r[1]));
}
static __device__ __forceinline__ float xsum32(float x) {
    u32x2 r = p32(__float_as_uint(x), __float_as_uint(x));
    return __uint_as_float(r[0]) + __uint_as_float(r[1]);
}

// ---------------------------------------------------------------------------
// Kernel 0: WT[n][k] = W[k][n] as bf16. n: 0-63 = Wq cols, 64-127 = Wk, 128-191 = Wv.
// ---------------------------------------------------------------------------
__global__ __launch_bounds__(256) void wtrans_kernel(
    const float* __restrict__ Wq, const float* __restrict__ Wk,
    const float* __restrict__ Wv, short* __restrict__ WT)
{
    const int n  = blockIdx.x;          // 0..191
    const int k0 = threadIdx.x * 4;     // 0..1020
    const float* Wsel = (n < 64) ? Wq : (n < 128 ? Wk : Wv);
    const int h = n & 63;
    short4 pk;
    pk.x = f2bf(Wsel[(size_t)(k0 + 0) * H_ + h]);
    pk.y = f2bf(Wsel[(size_t)(k0 + 1) * H_ + h]);
    pk.z = f2bf(Wsel[(size_t)(k0 + 2) * H_ + h]);
    pk.w = f2bf(Wsel[(size_t)(k0 + 3) * H_ + h]);
    *reinterpret_cast<short4*>(&WT[(size_t)n * C_ + k0]) = pk;
}

// ---------------------------------------------------------------------------
// Kernel 1: MFMA projections, software-pipelined (unchanged from round 9).
// ---------------------------------------------------------------------------
__global__ __launch_bounds__(256) void proj_kernel(
    const float* __restrict__ x, const short* __restrict__ WT,
    short* __restrict__ qg, short* __restrict__ kg, short* __restrict__ vT)
{
    __shared__ short Xs[32][72];
    __shared__ short Ws[192][72];

    const int tid  = threadIdx.x;
    const int m0   = blockIdx.x * 32;
    const int w    = tid >> 6;
    const int rs   = w >> 1;
    const int ch   = w & 1;
    const int lane = tid & 63;
    const int col  = lane & 15;
    const int g    = lane >> 4;

    const int srow = tid >> 3;
    const int sk0  = (tid & 7) * 8;
    const float* xs_src = &x[(size_t)(m0 + srow) * C_ + sk0];

    int wrow[6], wc8[6];
#pragma unroll
    for (int t6 = 0; t6 < 6; ++t6) {
        int idx = tid + t6 * 256;
        wrow[t6] = idx >> 3;
        wc8[t6]  = (idx & 7) * 8;
    }

    f32x4 acc[6];
#pragma unroll
    for (int nt = 0; nt < 6; ++nt) acc[nt] = (f32x4){0.f, 0.f, 0.f, 0.f};

    float4 xa0 = *reinterpret_cast<const float4*>(xs_src);
    float4 xb0 = *reinterpret_cast<const float4*>(xs_src + 4);
    float4 xa1 = *reinterpret_cast<const float4*>(xs_src + 64);
    float4 xb1 = *reinterpret_cast<const float4*>(xs_src + 68);
    bf16x8 wr[6];
#pragma unroll
    for (int t6 = 0; t6 < 6; ++t6)
        wr[t6] = *reinterpret_cast<const bf16x8*>(&WT[(size_t)wrow[t6] * C_ + wc8[t6]]);

#define PROJ_STEP(KB, XA, XB)                                                  \
    {                                                                          \
        __syncthreads();                                                       \
        u32x4 xw;                                                              \
        xw[0] = cvt_pk_bf16((XA).x, (XA).y);                                   \
        xw[1] = cvt_pk_bf16((XA).z, (XA).w);                                   \
        xw[2] = cvt_pk_bf16((XB).x, (XB).y);                                   \
        xw[3] = cvt_pk_bf16((XB).z, (XB).w);                                   \
        *reinterpret_cast<u32x4*>(&Xs[srow][sk0]) = xw;                        \
        _Pragma("unroll")                                                      \
        for (int t6 = 0; t6 < 6; ++t6)                                         \
            *reinterpret_cast<bf16x8*>(&Ws[wrow[t6]][wc8[t6]]) = wr[t6];       \
        __syncthreads();                                                       \
        if ((KB) + 128 < C_) {                                                 \
            XA = *reinterpret_cast<const float4*>(xs_src + (KB) + 128);        \
            XB = *reinterpret_cast<const float4*>(xs_src + (KB) + 132);        \
        }                                                                      \
        if ((KB) + 64 < C_) {                                                  \
            _Pragma("unroll")                                                  \
            for (int t6 = 0; t6 < 6; ++t6)                                     \
                wr[t6] = *reinterpret_cast<const bf16x8*>(                     \
                    &WT[(size_t)wrow[t6] * C_ + (KB) + 64 + wc8[t6]]);         \
        }                                                                      \
        bf16x8 a0 = *reinterpret_cast<const bf16x8*>(&Xs[rs * 16 + col][g * 8]);      \
        bf16x8 a1 = *reinterpret_cast<const bf16x8*>(&Xs[rs * 16 + col][32 + g * 8]); \
        _Pragma("unroll")                                                      \
        for (int nt = 0; nt < 6; ++nt) {                                       \
            const int ng = ch * 6 + nt;                                        \
            bf16x8 b0 = *reinterpret_cast<const bf16x8*>(&Ws[ng * 16 + col][g * 8]);      \
            bf16x8 b1 = *reinterpret_cast<const bf16x8*>(&Ws[ng * 16 + col][32 + g * 8]); \
            acc[nt] = __builtin_amdgcn_mfma_f32_16x16x32_bf16(a0, b0, acc[nt], 0, 0, 0);  \
            acc[nt] = __builtin_amdgcn_mfma_f32_16x16x32_bf16(a1, b1, acc[nt], 0, 0, 0);  \
        }                                                                      \
    }

    for (int s2 = 0; s2 < 8; ++s2) {
        const int kb = s2 * 128;
        PROJ_STEP(kb, xa0, xb0);
        PROJ_STEP(kb + 64, xa1, xb1);
    }
#undef PROJ_STEP

    const int trow0 = m0 + rs * 16 + g * 4;
    const int bb    = trow0 >> 11;
    const int tloc  = trow0 & 2047;
#pragma unroll
    for (int nt = 0; nt < 6; ++nt) {
        const int ng = ch * 6 + nt;
        if (ng < 4) {
#pragma unroll
            for (int r = 0; r < 4; ++r)
                qg[(size_t)(trow0 + r) * H_ + ng * 16 + col] = f2bf(acc[nt][r]);
        } else if (ng < 8) {
#pragma unroll
            for (int r = 0; r < 4; ++r)
                kg[(size_t)(trow0 + r) * H_ + (ng - 4) * 16 + col] = f2bf(acc[nt][r]);
        } else {
            short4 pk;
            pk.x = f2bf(acc[nt][0]); pk.y = f2bf(acc[nt][1]);
            pk.z = f2bf(acc[nt][2]); pk.w = f2bf(acc[nt][3]);
            const int h = (ng - 8) * 16 + col;
            *reinterpret_cast<short4*>(&vT[((size_t)bb * H_ + h) * T_ + tloc]) = pk;
        }
    }
}

// ---------------------------------------------------------------------------
// Kernel 2: MFMA flash attention. ONLY change vs round 9: launch bounds
// (512,4) -> (512). The (512,4) clause capped VGPR at 128; the live set
// (acc 32 + s 32 + qf 16 + va0 16 + temps ~25) exceeds that -> per-iteration
// scratch spills = the residual 10x slowdown. Spill-free > occupancy.
// ---------------------------------------------------------------------------
__global__ __launch_bounds__(512) void attn_kernel(
    const short* __restrict__ qg, const short* __restrict__ kg,
    const short* __restrict__ vT, float* __restrict__ out)
{
    __shared__ float Ob[8][32][68];    // per-wave partial O^T [w][q][h]
    __shared__ float Ml[8][32][2];     // per-wave (m, l)

    const int tid  = threadIdx.x;
    const int w    = tid >> 6;         // 0..7
    const int lane = tid & 63;
    const int ln   = lane & 31;        // q within tile / A-row
    const int hi   = lane >> 5;        // k-half selector
    const int bid  = blockIdx.x;
    const int b    = bid & 7;          // batch == XCD (round-robin dispatch)
    const int j    = 63 - (bid >> 3);  // longest q-tile first within XCD
    const int qt0  = j * 32;
    const int n64  = (j >> 1) + 1;     // 64-key blocks covering 0..qt0+31

    const size_t qkbase = (size_t)b * T_ * H_;

    bf16x8 qf[4];
#pragma unroll
    for (int ht = 0; ht < 4; ++ht)
        qf[ht] = *reinterpret_cast<const bf16x8*>(
            &qg[qkbase + (size_t)(qt0 + ln) * H_ + ht * 16 + hi * 8]);

    float m_i = -INFINITY, l_i = 0.f;
    f32x16 acc0, acc1;                 // O^T h 0..31 / 32..63
#pragma unroll
    for (int r = 0; r < 16; ++r) { acc0[r] = 0.f; acc1[r] = 0.f; }

    for (int kb = w; kb < n64; kb += 8) {
        const short* kbp = &kg[qkbase + (size_t)kb * 64 * H_];
        const short* vbp = &vT[(size_t)b * H_ * T_ + (size_t)kb * 64];

        // ---- S^T tiles ----
        f32x16 s0, s1;
#pragma unroll
        for (int r = 0; r < 16; ++r) { s0[r] = 0.f; s1[r] = 0.f; }
#pragma unroll
        for (int ht = 0; ht < 4; ++ht) {
            bf16x8 ka0 = *reinterpret_cast<const bf16x8*>(
                &kbp[(size_t)ln * H_ + ht * 16 + hi * 8]);
            bf16x8 ka1 = *reinterpret_cast<const bf16x8*>(
                &kbp[(size_t)(32 + ln) * H_ + ht * 16 + hi * 8]);
            s0 = __builtin_amdgcn_mfma_f32_32x32x16_bf16(ka0, qf[ht], s0, 0, 0, 0);
            s1 = __builtin_amdgcn_mfma_f32_32x32x16_bf16(ka1, qf[ht], s1, 0, 0, 0);
        }

        // ---- V^T first half issued early ----
        bf16x8 va0[4];
#pragma unroll
        for (int kt = 0; kt < 4; ++kt)
            va0[kt] = *reinterpret_cast<const bf16x8*>(
                &vbp[(size_t)ln * T_ + kt * 16 + hi * 8]);

        // ---- scale + causal mask (diagonal block only) ----
#pragma unroll
        for (int r = 0; r < 16; ++r) { s0[r] *= 0.03125f; s1[r] *= 0.03125f; }
        if (kb == n64 - 1) {
            const int qglob = qt0 + ln;
            const int kb0   = kb * 64 + hi * 4;
#pragma unroll
            for (int r = 0; r < 16; ++r) {
                const int key = kb0 + (r & 3) + 8 * (r >> 2);
                if (key > qglob)      s0[r] = -INFINITY;
                if (key + 32 > qglob) s1[r] = -INFINITY;
            }
        }

        // ---- lane-local softmax, tree max + 1 permlane swap ----
        float t8[8];
#pragma unroll
        for (int r = 0; r < 8; ++r)
            t8[r] = fmaxf(fmaxf(s0[r], s0[r + 8]), fmaxf(s1[r], s1[r + 8]));
#pragma unroll
        for (int r = 0; r < 4; ++r) t8[r] = fmaxf(t8[r], t8[r + 4]);
        float mx = fmaxf(fmaxf(t8[0], t8[2]), fmaxf(t8[1], t8[3]));
        mx = xmax32(mx);

        const float mn    = fmaxf(m_i, mx);
        const float alpha = __expf(m_i - mn);
        m_i = mn;

#pragma unroll
        for (int r = 0; r < 16; ++r) {
            s0[r] = __expf(s0[r] - mn);
            s1[r] = __expf(s1[r] - mn);
        }
#pragma unroll
        for (int r = 0; r < 8; ++r)
            t8[r] = (s0[r] + s0[r + 8]) + (s1[r] + s1[r + 8]);
#pragma unroll
        for (int r = 0; r < 4; ++r) t8[r] = t8[r] + t8[r + 4];
        float ls = (t8[0] + t8[2]) + (t8[1] + t8[3]);
        ls = xsum32(ls);
        l_i = l_i * alpha + ls;

#pragma unroll
        for (int r = 0; r < 16; ++r) { acc0[r] *= alpha; acc1[r] *= alpha; }

        // ---- pack P^T into B-fragments ----
        unsigned W0 = cvt_pk_bf16(s0[0],  s0[1]);
        unsigned W1 = cvt_pk_bf16(s0[2],  s0[3]);
        unsigned W2 = cvt_pk_bf16(s0[4],  s0[5]);
        unsigned W3 = cvt_pk_bf16(s0[6],  s0[7]);
        unsigned W4 = cvt_pk_bf16(s0[8],  s0[9]);
        unsigned W5 = cvt_pk_bf16(s0[10], s0[11]);
        unsigned W6 = cvt_pk_bf16(s0[12], s0[13]);
        unsigned W7 = cvt_pk_bf16(s0[14], s0[15]);
        u32x2 ra = p32(W0, W2), rb = p32(W1, W3);
        u32x4 bw0 = (u32x4){ra[0], rb[0], ra[1], rb[1]};   // keys 0..15
        ra = p32(W4, W6); rb = p32(W5, W7);
        u32x4 bw1 = (u32x4){ra[0], rb[0], ra[1], rb[1]};   // keys 16..31
        W0 = cvt_pk_bf16(s1[0],  s1[1]);
        W1 = cvt_pk_bf16(s1[2],  s1[3]);
        W2 = cvt_pk_bf16(s1[4],  s1[5]);
        W3 = cvt_pk_bf16(s1[6],  s1[7]);
        W4 = cvt_pk_bf16(s1[8],  s1[9]);
        W5 = cvt_pk_bf16(s1[10], s1[11]);
        W6 = cvt_pk_bf16(s1[12], s1[13]);
        W7 = cvt_pk_bf16(s1[14], s1[15]);
        ra = p32(W0, W2); rb = p32(W1, W3);
        u32x4 bw2 = (u32x4){ra[0], rb[0], ra[1], rb[1]};   // keys 32..47
        ra = p32(W4, W6); rb = p32(W5, W7);
        u32x4 bw3 = (u32x4){ra[0], rb[0], ra[1], rb[1]};   // keys 48..63
        bf16x8 pb0 = *reinterpret_cast<bf16x8*>(&bw0);
        bf16x8 pb1 = *reinterpret_cast<bf16x8*>(&bw1);
        bf16x8 pb2 = *reinterpret_cast<bf16x8*>(&bw2);
        bf16x8 pb3 = *reinterpret_cast<bf16x8*>(&bw3);

        // ---- V^T second half ----
        bf16x8 va1[4];
#pragma unroll
        for (int kt = 0; kt < 4; ++kt)
            va1[kt] = *reinterpret_cast<const bf16x8*>(
                &vbp[(size_t)(32 + ln) * T_ + kt * 16 + hi * 8]);

        // ---- O^T += V^T P^T ----
        acc0 = __builtin_amdgcn_mfma_f32_32x32x16_bf16(va0[0], pb0, acc0, 0, 0, 0);
        acc0 = __builtin_amdgcn_mfma_f32_32x32x16_bf16(va0[1], pb1, acc0, 0, 0, 0);
        acc0 = __builtin_amdgcn_mfma_f32_32x32x16_bf16(va0[2], pb2, acc0, 0, 0, 0);
        acc0 = __builtin_amdgcn_mfma_f32_32x32x16_bf16(va0[3], pb3, acc0, 0, 0, 0);
        acc1 = __builtin_amdgcn_mfma_f32_32x32x16_bf16(va1[0], pb0, acc1, 0, 0, 0);
        acc1 = __builtin_amdgcn_mfma_f32_32x32x16_bf16(va1[1], pb1, acc1, 0, 0, 0);
        acc1 = __builtin_amdgcn_mfma_f32_32x32x16_bf16(va1[2], pb2, acc1, 0, 0, 0);
        acc1 = __builtin_amdgcn_mfma_f32_32x32x16_bf16(va1[3], pb3, acc1, 0, 0, 0);
    }

    // ---- store partials: acc reg r -> h = (r&3) + 8*(r>>2) + 4*hi ----
#pragma unroll
    for (int part = 0; part < 4; ++part) {
        f32x4 v0 = (f32x4){acc0[part*4+0], acc0[part*4+1], acc0[part*4+2], acc0[part*4+3]};
        f32x4 v1 = (f32x4){acc1[part*4+0], acc1[part*4+1], acc1[part*4+2], acc1[part*4+3]};
        *reinterpret_cast<f32x4*>(&Ob[w][ln][hi * 4 + part * 8])      = v0;
        *reinterpret_cast<f32x4*>(&Ob[w][ln][32 + hi * 4 + part * 8]) = v1;
    }
    if (hi == 0) {
        Ml[w][ln][0] = m_i;
        Ml[w][ln][1] = l_i;
    }
    __syncthreads();

    // ---- 8-way merge; wave w covers h = w*8 + hi*4 .. +3 for q = ln ----
    float ms = -INFINITY;
#pragma unroll
    for (int w2 = 0; w2 < 8; ++w2) ms = fmaxf(ms, Ml[w2][ln][0]);
    float lsum = 0.f;
    float o[4];
#pragma unroll
    for (int e = 0; e < 4; ++e) o[e] = 0.f;
    const int h0 = w * 8 + hi * 4;
#pragma unroll
    for (int w2 = 0; w2 < 8; ++w2) {
        const float a = __expf(Ml[w2][ln][0] - ms);   // idle waves: exp(-inf)=0
        lsum += Ml[w2][ln][1] * a;
        const float* ob = &Ob[w2][ln][h0];
#pragma unroll
        for (int e = 0; e < 4; ++e) o[e] += a * ob[e];
    }
    const float inv = 1.f / lsum;
    f32x4 r0 = (f32x4){o[0] * inv, o[1] * inv, o[2] * inv, o[3] * inv};
    *reinterpret_cast<f32x4*>(&out[qkbase + (size_t)(qt0 + ln) * H_ + h0]) = r0;
}

// ---------------------------------------------------------------------------
extern "C" void kernel_launch(void* const* d_in, const int* in_sizes, int n_in,
                              void* d_out, int out_size, void* d_ws, size_t ws_size,
                              hipStream_t stream)
{
    // setup_inputs order: x, Wk, Wq, Wv
    const float* x  = (const float*)d_in[0];
    const float* Wk = (const float*)d_in[1];
    const float* Wq = (const float*)d_in[2];
    const float* Wv = (const float*)d_in[3];
    float* out = (float*)d_out;

    short* WT = (short*)d_ws;                       // [192][1024]
    short* qb = WT + (size_t)192 * C_;              // [B*T][64] bf16
    short* kb = qb + (size_t)B_ * T_ * H_;          // [B*T][64] bf16
    short* vT = kb + (size_t)B_ * T_ * H_;          // [B][64][T] bf16

    wtrans_kernel<<<dim3(192), 256, 0, stream>>>(Wq, Wk, Wv, WT);
    proj_kernel<<<dim3((B_ * T_) / 32), 256, 0, stream>>>(x, WT, qb, kb, vT);
    attn_kernel<<<dim3(T_ / 32 * B_), 512, 0, stream>>>(qb, kb, vT, out);
}

// Round 11
// 40.305 us; speedup vs baseline: 1.3441x; 1.3441x over previous
//
#include <hip/hip_runtime.h>
#include <math.h>

#define B_ 8
#define T_ 2048
#define C_ 1024
#define H_ 64

typedef __attribute__((ext_vector_type(8))) short bf16x8;
typedef __attribute__((ext_vector_type(4))) float f32x4;
typedef __attribute__((ext_vector_type(16))) float f32x16;
typedef __attribute__((ext_vector_type(4))) unsigned u32x4;
typedef __attribute__((ext_vector_type(2))) unsigned u32x2;

static __device__ __forceinline__ short f2bf(float f) {
    unsigned u = __float_as_uint(f);
    unsigned r = (u + 0x7FFFu + ((u >> 16) & 1u)) >> 16;   // RNE
    return (short)r;
}

// hardware packed f32->bf16 (RNE)
static __device__ __forceinline__ unsigned cvt_pk_bf16(float lo, float hi) {
    unsigned r;
    asm("v_cvt_pk_bf16_f32 %0, %1, %2" : "=v"(r) : "v"(lo), "v"(hi));
    return r;
}

// permlane swaps via builtins (return both results; alias-safe)
static __device__ __forceinline__ u32x2 p32(unsigned a, unsigned b) {
    return __builtin_amdgcn_permlane32_swap(a, b, false, false);
}
static __device__ __forceinline__ float xmax32(float x) {
    u32x2 r = p32(__float_as_uint(x), __float_as_uint(x));
    return fmaxf(__uint_as_float(r[0]), __uint_as_float(r[1]));
}
static __device__ __forceinline__ float xsum32(float x) {
    u32x2 r = p32(__float_as_uint(x), __float_as_uint(x));
    return __uint_as_float(r[0]) + __uint_as_float(r[1]);
}

// ---------------------------------------------------------------------------
// Fragment-linear workspace layouts (per batch, T*H shorts each):
//  qF[j][ht][lane][8]          : Q B-frag for 32-row tile j, h-tile ht
//  kF[kb][half][ht][lane][8]   : K A-frag for 64-key block kb (half=rows 0-31/32-63)
//  vF[kb][hs][kt][lane][8]     : V^T A-frag (hs = h-half, kt = key 16-tile)
// Every attn fragment load is then base + lane*16B -> fully coalesced 1KB.
// ---------------------------------------------------------------------------

// ---------------------------------------------------------------------------
// Kernel 0: WT[n][k] = W[k][n] as bf16. n: 0-63 = Wq cols, 64-127 = Wk, 128-191 = Wv.
// ---------------------------------------------------------------------------
__global__ __launch_bounds__(256) void wtrans_kernel(
    const float* __restrict__ Wq, const float* __restrict__ Wk,
    const float* __restrict__ Wv, short* __restrict__ WT)
{
    const int n  = blockIdx.x;          // 0..191
    const int k0 = threadIdx.x * 4;     // 0..1020
    const float* Wsel = (n < 64) ? Wq : (n < 128 ? Wk : Wv);
    const int h = n & 63;
    short4 pk;
    pk.x = f2bf(Wsel[(size_t)(k0 + 0) * H_ + h]);
    pk.y = f2bf(Wsel[(size_t)(k0 + 1) * H_ + h]);
    pk.z = f2bf(Wsel[(size_t)(k0 + 2) * H_ + h]);
    pk.w = f2bf(Wsel[(size_t)(k0 + 3) * H_ + h]);
    *reinterpret_cast<short4*>(&WT[(size_t)n * C_ + k0]) = pk;
}

// ---------------------------------------------------------------------------
// Kernel 1: MFMA projections, software-pipelined (compute unchanged from r9).
// Epilogue now writes q/k/v in fragment-linear layout (see above).
// ---------------------------------------------------------------------------
__global__ __launch_bounds__(256) void proj_kernel(
    const float* __restrict__ x, const short* __restrict__ WT,
    short* __restrict__ qF, short* __restrict__ kF, short* __restrict__ vF)
{
    __shared__ short Xs[32][72];
    __shared__ short Ws[192][72];

    const int tid  = threadIdx.x;
    const int m0   = blockIdx.x * 32;
    const int w    = tid >> 6;
    const int rs   = w >> 1;
    const int ch   = w & 1;
    const int lane = tid & 63;
    const int col  = lane & 15;
    const int g    = lane >> 4;

    const int srow = tid >> 3;
    const int sk0  = (tid & 7) * 8;
    const float* xs_src = &x[(size_t)(m0 + srow) * C_ + sk0];

    int wrow[6], wc8[6];
#pragma unroll
    for (int t6 = 0; t6 < 6; ++t6) {
        int idx = tid + t6 * 256;
        wrow[t6] = idx >> 3;
        wc8[t6]  = (idx & 7) * 8;
    }

    f32x4 acc[6];
#pragma unroll
    for (int nt = 0; nt < 6; ++nt) acc[nt] = (f32x4){0.f, 0.f, 0.f, 0.f};

    float4 xa0 = *reinterpret_cast<const float4*>(xs_src);
    float4 xb0 = *reinterpret_cast<const float4*>(xs_src + 4);
    float4 xa1 = *reinterpret_cast<const float4*>(xs_src + 64);
    float4 xb1 = *reinterpret_cast<const float4*>(xs_src + 68);
    bf16x8 wr[6];
#pragma unroll
    for (int t6 = 0; t6 < 6; ++t6)
        wr[t6] = *reinterpret_cast<const bf16x8*>(&WT[(size_t)wrow[t6] * C_ + wc8[t6]]);

#define PROJ_STEP(KB, XA, XB)                                                  \
    {                                                                          \
        __syncthreads();                                                       \
        u32x4 xw;                                                              \
        xw[0] = cvt_pk_bf16((XA).x, (XA).y);                                   \
        xw[1] = cvt_pk_bf16((XA).z, (XA).w);                                   \
        xw[2] = cvt_pk_bf16((XB).x, (XB).y);                                   \
        xw[3] = cvt_pk_bf16((XB).z, (XB).w);                                   \
        *reinterpret_cast<u32x4*>(&Xs[srow][sk0]) = xw;                        \
        _Pragma("unroll")                                                      \
        for (int t6 = 0; t6 < 6; ++t6)                                         \
            *reinterpret_cast<bf16x8*>(&Ws[wrow[t6]][wc8[t6]]) = wr[t6];       \
        __syncthreads();                                                       \
        if ((KB) + 128 < C_) {                                                 \
            XA = *reinterpret_cast<const float4*>(xs_src + (KB) + 128);        \
            XB = *reinterpret_cast<const float4*>(xs_src + (KB) + 132);        \
        }                                                                      \
        if ((KB) + 64 < C_) {                                                  \
            _Pragma("unroll")                                                  \
            for (int t6 = 0; t6 < 6; ++t6)                                     \
                wr[t6] = *reinterpret_cast<const bf16x8*>(                     \
                    &WT[(size_t)wrow[t6] * C_ + (KB) + 64 + wc8[t6]]);         \
        }                                                                      \
        bf16x8 a0 = *reinterpret_cast<const bf16x8*>(&Xs[rs * 16 + col][g * 8]);      \
        bf16x8 a1 = *reinterpret_cast<const bf16x8*>(&Xs[rs * 16 + col][32 + g * 8]); \
        _Pragma("unroll")                                                      \
        for (int nt = 0; nt < 6; ++nt) {                                       \
            const int ng = ch * 6 + nt;                                        \
            bf16x8 b0 = *reinterpret_cast<const bf16x8*>(&Ws[ng * 16 + col][g * 8]);      \
            bf16x8 b1 = *reinterpret_cast<const bf16x8*>(&Ws[ng * 16 + col][32 + g * 8]); \
            acc[nt] = __builtin_amdgcn_mfma_f32_16x16x32_bf16(a0, b0, acc[nt], 0, 0, 0);  \
            acc[nt] = __builtin_amdgcn_mfma_f32_16x16x32_bf16(a1, b1, acc[nt], 0, 0, 0);  \
        }                                                                      \
    }

    for (int s2 = 0; s2 < 8; ++s2) {
        const int kb = s2 * 128;
        PROJ_STEP(kb, xa0, xb0);
        PROJ_STEP(kb + 64, xa1, xb1);
    }
#undef PROJ_STEP

    // ---- epilogue: write fragment-linear layouts ----
    const int trow0 = m0 + rs * 16 + g * 4;
    const int bb    = trow0 >> 11;
    const int tloc  = trow0 & 2047;
    const size_t base = (size_t)bb * T_ * H_;
    const int hiq = col >> 3, eq = col & 7;   // fragment (hi, e) from output col
#pragma unroll
    for (int nt = 0; nt < 6; ++nt) {
        const int ng = ch * 6 + nt;
        if (ng < 4) {                       // Q: ht = ng
#pragma unroll
            for (int r = 0; r < 4; ++r) {
                const int tl  = tloc + r;
                const int jq  = tl >> 5, lnq = tl & 31;
                qF[base + (size_t)(((jq * 4 + ng) * 64) + hiq * 32 + lnq) * 8 + eq]
                    = f2bf(acc[nt][r]);
            }
        } else if (ng < 8) {                // K: ht = ng-4
#pragma unroll
            for (int r = 0; r < 4; ++r) {
                const int tl   = tloc + r;
                const int kb2  = tl >> 6, half = (tl >> 5) & 1, lnk = tl & 31;
                kF[base + (size_t)((((kb2 * 2 + half) * 4 + (ng - 4)) * 64)
                                   + hiq * 32 + lnk) * 8 + eq]
                    = f2bf(acc[nt][r]);
            }
        } else {                            // V^T: rows = h, cols = key
            const int kb2 = tloc >> 6, kt = (tloc >> 4) & 3;
            const int vhi = (tloc >> 3) & 1, e0 = tloc & 7;     // e0 in {0,4}
            const int h   = (ng - 8) * 16 + col;
            const int hs  = h >> 5, vln = h & 31;
            short4 pk;
            pk.x = f2bf(acc[nt][0]); pk.y = f2bf(acc[nt][1]);
            pk.z = f2bf(acc[nt][2]); pk.w = f2bf(acc[nt][3]);
            *reinterpret_cast<short4*>(
                &vF[base + (size_t)((((kb2 * 2 + hs) * 4 + kt) * 64)
                                    + vhi * 32 + vln) * 8 + e0]) = pk;
        }
    }
}

// ---------------------------------------------------------------------------
// Kernel 2: MFMA flash attention. ONLY change vs round 10: all Q/K/V loads
// come from fragment-linear buffers -> every load is base + lane*16B, one
// coalesced 1KB transaction (was a 32-segment 128B-strided gather).
// ---------------------------------------------------------------------------
__global__ __launch_bounds__(512) void attn_kernel(
    const short* __restrict__ qF, const short* __restrict__ kF,
    const short* __restrict__ vF, float* __restrict__ out)
{
    __shared__ float Ob[8][32][68];    // per-wave partial O^T [w][q][h]
    __shared__ float Ml[8][32][2];     // per-wave (m, l)

    const int tid  = threadIdx.x;
    const int w    = tid >> 6;         // 0..7
    const int lane = tid & 63;
    const int ln   = lane & 31;        // q within tile / A-row
    const int hi   = lane >> 5;        // k-half selector
    const int bid  = blockIdx.x;
    const int b    = bid & 7;          // batch == XCD (round-robin dispatch)
    const int j    = 63 - (bid >> 3);  // longest q-tile first within XCD
    const int qt0  = j * 32;
    const int n64  = (j >> 1) + 1;     // 64-key blocks covering 0..qt0+31

    const size_t base = (size_t)b * T_ * H_;
    const short* qFb = qF + base;
    const short* kFb = kF + base;
    const short* vFb = vF + base;

    bf16x8 qf[4];
#pragma unroll
    for (int ht = 0; ht < 4; ++ht)
        qf[ht] = *reinterpret_cast<const bf16x8*>(
            &qFb[(size_t)((j * 4 + ht) * 64 + lane) * 8]);

    float m_i = -INFINITY, l_i = 0.f;
    f32x16 acc0, acc1;                 // O^T h 0..31 / 32..63
#pragma unroll
    for (int r = 0; r < 16; ++r) { acc0[r] = 0.f; acc1[r] = 0.f; }

    for (int kb = w; kb < n64; kb += 8) {
        const short* kblk = &kFb[(size_t)kb * 4096];   // 2 halves x 4 ht x 64 x 8
        const short* vblk = &vFb[(size_t)kb * 4096];   // 2 hs x 4 kt x 64 x 8

        // ---- S^T tiles (coalesced fragment loads) ----
        f32x16 s0, s1;
#pragma unroll
        for (int r = 0; r < 16; ++r) { s0[r] = 0.f; s1[r] = 0.f; }
#pragma unroll
        for (int ht = 0; ht < 4; ++ht) {
            bf16x8 ka0 = *reinterpret_cast<const bf16x8*>(
                &kblk[(size_t)((ht * 64) + lane) * 8]);
            bf16x8 ka1 = *reinterpret_cast<const bf16x8*>(
                &kblk[(size_t)(((4 + ht) * 64) + lane) * 8]);
            s0 = __builtin_amdgcn_mfma_f32_32x32x16_bf16(ka0, qf[ht], s0, 0, 0, 0);
            s1 = __builtin_amdgcn_mfma_f32_32x32x16_bf16(ka1, qf[ht], s1, 0, 0, 0);
        }

        // ---- V^T first half issued early ----
        bf16x8 va0[4];
#pragma unroll
        for (int kt = 0; kt < 4; ++kt)
            va0[kt] = *reinterpret_cast<const bf16x8*>(
                &vblk[(size_t)((kt * 64) + lane) * 8]);

        // ---- scale + causal mask (diagonal block only) ----
#pragma unroll
        for (int r = 0; r < 16; ++r) { s0[r] *= 0.03125f; s1[r] *= 0.03125f; }
        if (kb == n64 - 1) {
            const int qglob = qt0 + ln;
            const int kb0   = kb * 64 + hi * 4;
#pragma unroll
            for (int r = 0; r < 16; ++r) {
                const int key = kb0 + (r & 3) + 8 * (r >> 2);
                if (key > qglob)      s0[r] = -INFINITY;
                if (key + 32 > qglob) s1[r] = -INFINITY;
            }
        }

        // ---- lane-local softmax, tree max + 1 permlane swap ----
        float t8[8];
#pragma unroll
        for (int r = 0; r < 8; ++r)
            t8[r] = fmaxf(fmaxf(s0[r], s0[r + 8]), fmaxf(s1[r], s1[r + 8]));
#pragma unroll
        for (int r = 0; r < 4; ++r) t8[r] = fmaxf(t8[r], t8[r + 4]);
        float mx = fmaxf(fmaxf(t8[0], t8[2]), fmaxf(t8[1], t8[3]));
        mx = xmax32(mx);

        const float mn    = fmaxf(m_i, mx);
        const float alpha = __expf(m_i - mn);
        m_i = mn;

#pragma unroll
        for (int r = 0; r < 16; ++r) {
            s0[r] = __expf(s0[r] - mn);
            s1[r] = __expf(s1[r] - mn);
        }
#pragma unroll
        for (int r = 0; r < 8; ++r)
            t8[r] = (s0[r] + s0[r + 8]) + (s1[r] + s1[r + 8]);
#pragma unroll
        for (int r = 0; r < 4; ++r) t8[r] = t8[r] + t8[r + 4];
        float ls = (t8[0] + t8[2]) + (t8[1] + t8[3]);
        ls = xsum32(ls);
        l_i = l_i * alpha + ls;

#pragma unroll
        for (int r = 0; r < 16; ++r) { acc0[r] *= alpha; acc1[r] *= alpha; }

        // ---- pack P^T into B-fragments ----
        unsigned W0 = cvt_pk_bf16(s0[0],  s0[1]);
        unsigned W1 = cvt_pk_bf16(s0[2],  s0[3]);
        unsigned W2 = cvt_pk_bf16(s0[4],  s0[5]);
        unsigned W3 = cvt_pk_bf16(s0[6],  s0[7]);
        unsigned W4 = cvt_pk_bf16(s0[8],  s0[9]);
        unsigned W5 = cvt_pk_bf16(s0[10], s0[11]);
        unsigned W6 = cvt_pk_bf16(s0[12], s0[13]);
        unsigned W7 = cvt_pk_bf16(s0[14], s0[15]);
        u32x2 ra = p32(W0, W2), rb = p32(W1, W3);
        u32x4 bw0 = (u32x4){ra[0], rb[0], ra[1], rb[1]};   // keys 0..15
        ra = p32(W4, W6); rb = p32(W5, W7);
        u32x4 bw1 = (u32x4){ra[0], rb[0], ra[1], rb[1]};   // keys 16..31
        W0 = cvt_pk_bf16(s1[0],  s1[1]);
        W1 = cvt_pk_bf16(s1[2],  s1[3]);
        W2 = cvt_pk_bf16(s1[4],  s1[5]);
        W3 = cvt_pk_bf16(s1[6],  s1[7]);
        W4 = cvt_pk_bf16(s1[8],  s1[9]);
        W5 = cvt_pk_bf16(s1[10], s1[11]);
        W6 = cvt_pk_bf16(s1[12], s1[13]);
        W7 = cvt_pk_bf16(s1[14], s1[15]);
        ra = p32(W0, W2); rb = p32(W1, W3);
        u32x4 bw2 = (u32x4){ra[0], rb[0], ra[1], rb[1]};   // keys 32..47
        ra = p32(W4, W6); rb = p32(W5, W7);
        u32x4 bw3 = (u32x4){ra[0], rb[0], ra[1], rb[1]};   // keys 48..63
        bf16x8 pb0 = *reinterpret_cast<bf16x8*>(&bw0);
        bf16x8 pb1 = *reinterpret_cast<bf16x8*>(&bw1);
        bf16x8 pb2 = *reinterpret_cast<bf16x8*>(&bw2);
        bf16x8 pb3 = *reinterpret_cast<bf16x8*>(&bw3);

        // ---- V^T second half ----
        bf16x8 va1[4];
#pragma unroll
        for (int kt = 0; kt < 4; ++kt)
            va1[kt] = *reinterpret_cast<const bf16x8*>(
                &vblk[(size_t)(((4 + kt) * 64) + lane) * 8]);

        // ---- O^T += V^T P^T ----
        acc0 = __builtin_amdgcn_mfma_f32_32x32x16_bf16(va0[0], pb0, acc0, 0, 0, 0);
        acc0 = __builtin_amdgcn_mfma_f32_32x32x16_bf16(va0[1], pb1, acc0, 0, 0, 0);
        acc0 = __builtin_amdgcn_mfma_f32_32x32x16_bf16(va0[2], pb2, acc0, 0, 0, 0);
        acc0 = __builtin_amdgcn_mfma_f32_32x32x16_bf16(va0[3], pb3, acc0, 0, 0, 0);
        acc1 = __builtin_amdgcn_mfma_f32_32x32x16_bf16(va1[0], pb0, acc1, 0, 0, 0);
        acc1 = __builtin_amdgcn_mfma_f32_32x32x16_bf16(va1[1], pb1, acc1, 0, 0, 0);
        acc1 = __builtin_amdgcn_mfma_f32_32x32x16_bf16(va1[2], pb2, acc1, 0, 0, 0);
        acc1 = __builtin_amdgcn_mfma_f32_32x32x16_bf16(va1[3], pb3, acc1, 0, 0, 0);
    }

    // ---- store partials: acc reg r -> h = (r&3) + 8*(r>>2) + 4*hi ----
#pragma unroll
    for (int part = 0; part < 4; ++part) {
        f32x4 v0 = (f32x4){acc0[part*4+0], acc0[part*4+1], acc0[part*4+2], acc0[part*4+3]};
        f32x4 v1 = (f32x4){acc1[part*4+0], acc1[part*4+1], acc1[part*4+2], acc1[part*4+3]};
        *reinterpret_cast<f32x4*>(&Ob[w][ln][hi * 4 + part * 8])      = v0;
        *reinterpret_cast<f32x4*>(&Ob[w][ln][32 + hi * 4 + part * 8]) = v1;
    }
    if (hi == 0) {
        Ml[w][ln][0] = m_i;
        Ml[w][ln][1] = l_i;
    }
    __syncthreads();

    // ---- 8-way merge; wave w covers h = w*8 + hi*4 .. +3 for q = ln ----
    float ms = -INFINITY;
#pragma unroll
    for (int w2 = 0; w2 < 8; ++w2) ms = fmaxf(ms, Ml[w2][ln][0]);
    float lsum = 0.f;
    float o[4];
#pragma unroll
    for (int e = 0; e < 4; ++e) o[e] = 0.f;
    const int h0 = w * 8 + hi * 4;
#pragma unroll
    for (int w2 = 0; w2 < 8; ++w2) {
        const float a = __expf(Ml[w2][ln][0] - ms);   // idle waves: exp(-inf)=0
        lsum += Ml[w2][ln][1] * a;
        const float* ob = &Ob[w2][ln][h0];
#pragma unroll
        for (int e = 0; e < 4; ++e) o[e] += a * ob[e];
    }
    const float inv = 1.f / lsum;
    f32x4 r0 = (f32x4){o[0] * inv, o[1] * inv, o[2] * inv, o[3] * inv};
    *reinterpret_cast<f32x4*>(&out[base + (size_t)(qt0 + ln) * H_ + h0]) = r0;
}

// ---------------------------------------------------------------------------
extern "C" void kernel_launch(void* const* d_in, const int* in_sizes, int n_in,
                              void* d_out, int out_size, void* d_ws, size_t ws_size,
                              hipStream_t stream)
{
    // setup_inputs order: x, Wk, Wq, Wv
    const float* x  = (const float*)d_in[0];
    const float* Wk = (const float*)d_in[1];
    const float* Wq = (const float*)d_in[2];
    const float* Wv = (const float*)d_in[3];
    float* out = (float*)d_out;

    short* WT = (short*)d_ws;                       // [192][1024]
    short* qF = WT + (size_t)192 * C_;              // fragment-linear Q
    short* kF = qF + (size_t)B_ * T_ * H_;          // fragment-linear K
    short* vF = kF + (size_t)B_ * T_ * H_;          // fragment-linear V^T

    wtrans_kernel<<<dim3(192), 256, 0, stream>>>(Wq, Wk, Wv, WT);
    proj_kernel<<<dim3((B_ * T_) / 32), 256, 0, stream>>>(x, WT, qF, kF, vF);
    attn_kernel<<<dim3(T_ / 32 * B_), 512, 0, stream>>>(qF, kF, vF, out);
}